// Round 7
// baseline (445.095 us; speedup 1.0000x reference)
//
#include <hip/hip_runtime.h>

// ChebNet classifier: 3x ChebConv(K=6) + 2x sparse pool + linear head.
// R6: out-GEMMs were vmem-ISSUE bound (80 float4 loads / 512 flops per
//     thread = 6.4 f/l; 1.5M wave-loads @ ~8cy = the 51us). Node-tiled
//     NT=5 outsplit: 9 loads -> 80 FMAs per chunk (17.8 f/l, 2.8x fewer
//     vmem instrs). wcol computation fused into scatter_all.

#define TPB 256

static inline int gs(long long n) { return (int)((n + TPB - 1) / TPB); }

struct Desc5 {
    const int* rows[5];
    const int* cols[5];
    const float* vals[5];
    int eoff[6];
    int doff[5];
};

struct TxPtrs { const float* p[6]; };

// ---------- batched CSR build ----------

__global__ void k_count_all(Desc5 d, int* __restrict__ cnt, int Etot) {
    int e = blockIdx.x * blockDim.x + threadIdx.x;
    if (e >= Etot) return;
    int s = 0;
    while (e >= d.eoff[s + 1]) ++s;
    int le = e - d.eoff[s];
    atomicAdd(&cnt[d.doff[s] + d.rows[s][le]], 1);
}

__global__ void k_scan1(const int* __restrict__ cnt, int* __restrict__ excl,
                        int* __restrict__ bsum, int n) {
    int gid = blockIdx.x * 256 + threadIdx.x;
    int v = (gid < n) ? cnt[gid] : 0;
    int lane = threadIdx.x & 63, wid = threadIdx.x >> 6;
    int s = v;
#pragma unroll
    for (int off = 1; off < 64; off <<= 1) {
        int t = __shfl_up(s, off, 64);
        if (lane >= off) s += t;
    }
    __shared__ int wsum[4];
    if (lane == 63) wsum[wid] = s;
    __syncthreads();
    int add = 0;
    for (int w = 0; w < wid; ++w) add += wsum[w];
    if (gid < n) excl[gid] = add + s - v;
    if (threadIdx.x == 255) bsum[blockIdx.x] = add + s;
}

__global__ void k_scan2(int* __restrict__ bsum, int nb) {
    int lane = threadIdx.x;  // blockDim = 64
    int carry = 0;
    for (int base = 0; base < nb; base += 64) {
        int i = base + lane;
        int v = (i < nb) ? bsum[i] : 0;
        int s = v;
#pragma unroll
        for (int off = 1; off < 64; off <<= 1) {
            int t = __shfl_up(s, off, 64);
            if (lane >= off) s += t;
        }
        if (i < nb) bsum[i] = carry + s - v;
        carry += __shfl(s, 63, 64);
    }
}

__global__ void k_scan3(int* __restrict__ rowptr, const int* __restrict__ bsum,
                        int n, int E) {
    int gid = blockIdx.x * 256 + threadIdx.x;
    if (gid < n) rowptr[gid] += bsum[blockIdx.x];
    if (gid == 0) rowptr[n] = E;
}

__global__ void k_dinv_i(const int* __restrict__ cnt, float* __restrict__ dinv, int n) {
    int i = blockIdx.x * blockDim.x + threadIdx.x;
    if (i < n) {
        int d = cnt[i];
        dinv[i] = d > 0 ? 1.0f / sqrtf((float)d) : 0.f;
    }
}

// scatter edges into CSR slots; for graph segments (s<3) also emit
// wcol[pos] = dinv[col] (dinv_i has already run).
__global__ void k_scatter_all(Desc5 d, const int* __restrict__ rowptr,
                              int* __restrict__ cursor, int* __restrict__ colsp,
                              float* __restrict__ valsp, float* __restrict__ wcol,
                              const float* __restrict__ dinv, int Etot) {
    int e = blockIdx.x * blockDim.x + threadIdx.x;
    if (e >= Etot) return;
    int s = 0;
    while (e >= d.eoff[s + 1]) ++s;
    int le = e - d.eoff[s];
    int gr = d.doff[s] + d.rows[s][le];
    int pos = rowptr[gr] + atomicAdd(&cursor[gr], 1);
    int cv = d.cols[s][le];
    colsp[pos] = cv;
    if (s < 3) wcol[pos] = dinv[d.doff[s] + cv];
    else       valsp[pos] = d.vals[s][le];
}

// pos (N0 x 3) -> pos4 (N0 x 4, w = 0)
__global__ void k_pad4(const float* __restrict__ pos, float4* __restrict__ pos4, int n) {
    int i = blockIdx.x * blockDim.x + threadIdx.x;
    if (i < n) pos4[i] = make_float4(pos[3 * i], pos[3 * i + 1], pos[3 * i + 2], 0.f);
}

// ---------- gather SpMV (Cheb prop) ----------
// acc = sum_j wcol_j * src[col_j]; prop = -dinv[r]*acc
// mode 0: dst = prop ; mode 1: dst = 2*prop - prev

template <int C>
__global__ void k_sprop_t(const int* __restrict__ rowptr, const int* __restrict__ colsp,
                          const float* __restrict__ wcol, const float* __restrict__ dinv,
                          const float* __restrict__ src, const float* __restrict__ prev,
                          float* __restrict__ dst, int n, int mode) {
    constexpr int C4 = C / 4;
    int idx = blockIdx.x * blockDim.x + threadIdx.x;
    if (idx >= n * C4) return;
    int r = idx / C4, c4 = (idx - r * C4) * 4;
    int s0 = rowptr[r], s1 = rowptr[r + 1];
    float4 acca = make_float4(0.f, 0.f, 0.f, 0.f);
    float4 accb = make_float4(0.f, 0.f, 0.f, 0.f);
    int j = s0;
    for (; j + 2 <= s1; j += 2) {
        int ca = colsp[j], cb = colsp[j + 1];
        float wa = wcol[j], wb = wcol[j + 1];
        float4 sa = *(const float4*)(src + (long long)ca * C + c4);
        float4 sb = *(const float4*)(src + (long long)cb * C + c4);
        acca.x += wa * sa.x; acca.y += wa * sa.y; acca.z += wa * sa.z; acca.w += wa * sa.w;
        accb.x += wb * sb.x; accb.y += wb * sb.y; accb.z += wb * sb.z; accb.w += wb * sb.w;
    }
    if (j < s1) {
        int c = colsp[j];
        float w = wcol[j];
        float4 s = *(const float4*)(src + (long long)c * C + c4);
        acca.x += w * s.x; acca.y += w * s.y; acca.z += w * s.z; acca.w += w * s.w;
    }
    acca.x += accb.x; acca.y += accb.y; acca.z += accb.z; acca.w += accb.w;
    float m = -dinv[r];
    long long o = (long long)r * C + c4;
    float4 out;
    if (mode) {
        float4 p = *(const float4*)(prev + o);
        out.x = 2.f * m * acca.x - p.x; out.y = 2.f * m * acca.y - p.y;
        out.z = 2.f * m * acca.z - p.z; out.w = 2.f * m * acca.w - p.w;
    } else {
        out.x = m * acca.x; out.y = m * acca.y; out.z = m * acca.z; out.w = m * acca.w;
    }
    *(float4*)(dst + o) = out;
}

// ---------- pool0: out[r] = sum_j vals_j * relu(x[col_j]) ----------

template <int C>
__global__ void k_spool4_t(const int* __restrict__ rowptr, const int* __restrict__ colsp,
                           const float* __restrict__ valsp, const float* __restrict__ x,
                           float* __restrict__ out, int n) {
    constexpr int C4 = C / 4;
    int idx = blockIdx.x * blockDim.x + threadIdx.x;
    if (idx >= n * C4) return;
    int r = idx / C4, c4 = (idx - r * C4) * 4;
    int s0 = rowptr[r], s1 = rowptr[r + 1];
    float4 acca = make_float4(0.f, 0.f, 0.f, 0.f);
    float4 accb = make_float4(0.f, 0.f, 0.f, 0.f);
    int j = s0;
    for (; j + 2 <= s1; j += 2) {
        int ca = colsp[j], cb = colsp[j + 1];
        float va = valsp[j], vb = valsp[j + 1];
        float4 sa = *(const float4*)(x + (long long)ca * C + c4);
        float4 sb = *(const float4*)(x + (long long)cb * C + c4);
        acca.x += va * fmaxf(sa.x, 0.f); acca.y += va * fmaxf(sa.y, 0.f);
        acca.z += va * fmaxf(sa.z, 0.f); acca.w += va * fmaxf(sa.w, 0.f);
        accb.x += vb * fmaxf(sb.x, 0.f); accb.y += vb * fmaxf(sb.y, 0.f);
        accb.z += vb * fmaxf(sb.z, 0.f); accb.w += vb * fmaxf(sb.w, 0.f);
    }
    if (j < s1) {
        int c = colsp[j];
        float v = valsp[j];
        float4 s = *(const float4*)(x + (long long)c * C + c4);
        acca.x += v * fmaxf(s.x, 0.f); acca.y += v * fmaxf(s.y, 0.f);
        acca.z += v * fmaxf(s.z, 0.f); acca.w += v * fmaxf(s.w, 0.f);
    }
    acca.x += accb.x; acca.y += accb.y; acca.z += accb.z; acca.w += accb.w;
    *(float4*)(out + (long long)r * C + c4) = acca;
}

// ---------- pool1 fused with layer-1 partial reduce + bias + relu ----------

template <int C, int KSPLIT>
__global__ void k_pool_f(const int* __restrict__ rowptr, const int* __restrict__ colsp,
                         const float* __restrict__ valsp, const float* __restrict__ part,
                         const float* __restrict__ bias, float* __restrict__ out,
                         int n, int partStride) {
    constexpr int C4 = C / 4;
    int idx = blockIdx.x * blockDim.x + threadIdx.x;
    if (idx >= n * C4) return;
    int r = idx / C4, c4 = (idx - r * C4) * 4;
    int s0 = rowptr[r], s1 = rowptr[r + 1];
    float4 bb = *(const float4*)(bias + c4);
    float4 acc = make_float4(0.f, 0.f, 0.f, 0.f);
    for (int j = s0; j < s1; ++j) {
        int c = colsp[j];
        float v = valsp[j];
        float4 x = bb;
#pragma unroll
        for (int s = 0; s < KSPLIT; ++s) {
            float4 p = *(const float4*)(part + (long long)s * partStride + (long long)c * C + c4);
            x.x += p.x; x.y += p.y; x.z += p.z; x.w += p.w;
        }
        acc.x += v * fmaxf(x.x, 0.f); acc.y += v * fmaxf(x.y, 0.f);
        acc.z += v * fmaxf(x.z, 0.f); acc.w += v * fmaxf(x.w, 0.f);
    }
    *(float4*)(out + (long long)r * C + c4) = acc;
}

// ---------- layer-0 direct out-GEMM (CIN=3 stride 4, COUT=32) ----------

__global__ void k_outgemm0(float* __restrict__ out, TxPtrs txs,
                           const float* __restrict__ W, const float* __restrict__ b,
                           int n) {
    int idx = blockIdx.x * blockDim.x + threadIdx.x;
    if (idx >= n * 8) return;
    int node = idx >> 3, co = (idx & 7) * 4;
    float4 acc = *(const float4*)(b + co);
#pragma unroll
    for (int k = 0; k < 6; ++k) {
        float4 xv = ((const float4*)txs.p[k])[node];
        const float* Wk = W + k * 96 + co;
        float4 w0 = *(const float4*)(Wk);
        float4 w1 = *(const float4*)(Wk + 32);
        float4 w2 = *(const float4*)(Wk + 64);
        acc.x += xv.x * w0.x + xv.y * w1.x + xv.z * w2.x;
        acc.y += xv.x * w0.y + xv.y * w1.y + xv.z * w2.y;
        acc.z += xv.x * w0.z + xv.y * w1.z + xv.z * w2.z;
        acc.w += xv.x * w0.w + xv.y * w1.w + xv.z * w2.w;
    }
    *(float4*)(out + (long long)node * 32 + co) = acc;
}

// ---------- node-tiled k-split out-GEMM ----------
// Thread computes NT nodes x 4 cols for KPER k-values: per ci4-chunk
// NT+4 loads -> NT*16 FMAs. Requires n % NT == 0.

template <int CIN, int COUT, int KSPLIT, int NT>
__global__ void k_outsplit_nt(float* __restrict__ part, TxPtrs txs,
                              const float* __restrict__ W, int n, int partStride) {
    constexpr int CO4 = COUT / 4;
    constexpr int KPER = 6 / KSPLIT;
    int ntile = n / NT;
    int per = ntile * CO4;
    int idx = blockIdx.x * blockDim.x + threadIdx.x;
    if (idx >= per * KSPLIT) return;
    int s = idx / per, t = idx - s * per;
    int tile = t / CO4, co = (t - tile * CO4) * 4;
    int node0 = tile * NT;
    float4 acc[NT];
#pragma unroll
    for (int i = 0; i < NT; ++i) acc[i] = make_float4(0.f, 0.f, 0.f, 0.f);
#pragma unroll
    for (int kk = 0; kk < KPER; ++kk) {
        int k = s * KPER + kk;
        const float* xb = txs.p[k] + (long long)node0 * CIN;
        const float* Wk = W + (long long)k * CIN * COUT + co;
#pragma unroll
        for (int c4 = 0; c4 < CIN / 4; ++c4) {
            float4 xv[NT];
#pragma unroll
            for (int i = 0; i < NT; ++i)
                xv[i] = *(const float4*)(xb + (long long)i * CIN + c4 * 4);
            const float* Wr = Wk + c4 * 4 * COUT;
            float4 w0 = *(const float4*)(Wr);
            float4 w1 = *(const float4*)(Wr + COUT);
            float4 w2 = *(const float4*)(Wr + 2 * COUT);
            float4 w3 = *(const float4*)(Wr + 3 * COUT);
#pragma unroll
            for (int i = 0; i < NT; ++i) {
                acc[i].x += xv[i].x * w0.x + xv[i].y * w1.x + xv[i].z * w2.x + xv[i].w * w3.x;
                acc[i].y += xv[i].x * w0.y + xv[i].y * w1.y + xv[i].z * w2.y + xv[i].w * w3.y;
                acc[i].z += xv[i].x * w0.z + xv[i].y * w1.z + xv[i].z * w2.z + xv[i].w * w3.z;
                acc[i].w += xv[i].x * w0.w + xv[i].y * w1.w + xv[i].z * w2.w + xv[i].w * w3.w;
            }
        }
    }
    float* op = part + (long long)s * partStride + (long long)node0 * COUT + co;
#pragma unroll
    for (int i = 0; i < NT; ++i)
        *(float4*)(op + (long long)i * COUT) = acc[i];
}

// ---------- linear head, fused with layer-2 partial reduce + bias ----------

__global__ void k_linear_partial_f(const float* __restrict__ lw,
                                   const float4* __restrict__ part,
                                   const float* __restrict__ b2,
                                   float* __restrict__ partials,
                                   int len4, int len, int nblk) {
    float acc[10];
#pragma unroll
    for (int j = 0; j < 10; ++j) acc[j] = 0.f;
    const float4* b2v = (const float4*)b2;
    for (int i = blockIdx.x * blockDim.x + threadIdx.x; i < len4;
         i += gridDim.x * blockDim.x) {
        float4 xv = b2v[i & 31];
#pragma unroll
        for (int s = 0; s < 6; ++s) {
            float4 p = part[s * 200000 + i];
            xv.x += p.x; xv.y += p.y; xv.z += p.z; xv.w += p.w;
        }
#pragma unroll
        for (int j = 0; j < 10; ++j) {
            float4 wv = *(const float4*)(lw + (long long)j * len + i * 4);
            acc[j] += xv.x * wv.x + xv.y * wv.y + xv.z * wv.z + xv.w * wv.w;
        }
    }
    __shared__ float lds[4][10];
    int wid = threadIdx.x >> 6, lane = threadIdx.x & 63;
#pragma unroll
    for (int j = 0; j < 10; ++j) {
        float v = acc[j];
        for (int off = 32; off > 0; off >>= 1) v += __shfl_down(v, off, 64);
        if (lane == 0) lds[wid][j] = v;
    }
    __syncthreads();
    if (threadIdx.x < 10) {
        float s = lds[0][threadIdx.x] + lds[1][threadIdx.x] +
                  lds[2][threadIdx.x] + lds[3][threadIdx.x];
        partials[threadIdx.x * nblk + blockIdx.x] = s;
    }
}

__global__ void k_linear_final(const float* __restrict__ partials,
                               const float* __restrict__ lb,
                               float* __restrict__ out, int nblk) {
    int j = threadIdx.x >> 6, lane = threadIdx.x & 63;
    float v = 0.f;
    for (int b = lane; b < nblk; b += 64) v += partials[j * nblk + b];
    for (int off = 32; off > 0; off >>= 1) v += __shfl_down(v, off, 64);
    if (lane == 0) out[j] = lb[j] + v;
}

extern "C" void kernel_launch(void* const* d_in, const int* in_sizes, int n_in,
                              void* d_out, int out_size, void* d_ws, size_t ws_size,
                              hipStream_t stream) {
    const int cN0 = 100000, cN1 = 25000, cN2 = 6250;
    const int cE0 = 600000, cE1 = 150000, cE2 = 40000;
    const int NBLK = 512;

    const float* pos = (const float*)d_in[0];
    const int*   ei0 = (const int*)d_in[1];
    const int*   ei1 = (const int*)d_in[2];
    const int*   ei2 = (const int*)d_in[3];
    const int*   d0r = (const int*)d_in[4];
    const int*   d0c = (const int*)d_in[5];
    const float* d0v = (const float*)d_in[6];
    const int*   d1r = (const int*)d_in[7];
    const int*   d1c = (const int*)d_in[8];
    const float* d1v = (const float*)d_in[9];
    const float* W0  = (const float*)d_in[10];
    const float* b0  = (const float*)d_in[11];
    const float* W1  = (const float*)d_in[12];
    const float* b1  = (const float*)d_in[13];
    const float* W2  = (const float*)d_in[14];
    const float* b2  = (const float*)d_in[15];
    const float* lw  = (const float*)d_in[16];
    const float* lb  = (const float*)d_in[17];
    float* outZ = (float*)d_out;

    // concatenated row space: g0 g1 g2 p0 p1
    const int ntot = cN0 + cN1 + cN2 + cN1 + cN2;          // 162500
    const int Etot = cE0 + cE1 + cE2 + cN0 + cN1;          // 915000
    const int Eg   = cE0 + cE1 + cE2;                      // 790000 (graph edges)
    const int doff0 = 0, doff1 = cN0, doff2 = cN0 + cN1,
              doffp0 = doff2 + cN2, doffp1 = doffp0 + cN1;

    // workspace layout (4B units); all float4 bases 16B-aligned
    int*   iws    = (int*)d_ws;
    int*   ideg   = iws;                         // 162500
    int*   cursor = ideg + 162500;               // 162500 (adjacent: one memset)
    int*   rowptr = cursor + 162500;             // 162504
    int*   bsum   = rowptr + 162504;             // 704
    float* dinv   = (float*)(bsum + 704);        // 131256
    int*   colsp  = (int*)(dinv + 131256);       // 915000
    float* valsp  = (float*)(colsp + 915000);    // 915000
    float* wcol   = valsp + 915000;              // 790000
    float* pos4   = wcol + 790000;               // 400000
    float* txbuf  = pos4 + 400000;               // 5 x 800000
    float* part   = txbuf + 5 * 800000;          // 4800000
    float* bufOut = part + 4800000;              // 3200000
    float* bufPool= bufOut + 3200000;            // 800000
    float* lpart  = bufPool + 800000;            // 5120

    // ---- independent prep ----
    k_pad4<<<gs(cN0), TPB, 0, stream>>>(pos, (float4*)pos4, cN0);

    // ---- batched CSR build ----
    Desc5 d;
    d.rows[0] = ei0;        d.cols[0] = ei0 + cE0; d.vals[0] = nullptr;
    d.rows[1] = ei1;        d.cols[1] = ei1 + cE1; d.vals[1] = nullptr;
    d.rows[2] = ei2;        d.cols[2] = ei2 + cE2; d.vals[2] = nullptr;
    d.rows[3] = d0r;        d.cols[3] = d0c;       d.vals[3] = d0v;
    d.rows[4] = d1r;        d.cols[4] = d1c;       d.vals[4] = d1v;
    d.eoff[0] = 0;
    d.eoff[1] = cE0;
    d.eoff[2] = cE0 + cE1;
    d.eoff[3] = Eg;
    d.eoff[4] = Eg + cN0;
    d.eoff[5] = Etot;
    d.doff[0] = doff0; d.doff[1] = doff1; d.doff[2] = doff2;
    d.doff[3] = doffp0; d.doff[4] = doffp1;

    hipMemsetAsync(ideg, 0, (size_t)(162500 + 162500) * 4, stream);
    k_count_all<<<gs(Etot), TPB, 0, stream>>>(d, ideg, Etot);
    int nb = (ntot + 255) / 256;
    k_scan1<<<nb, 256, 0, stream>>>(ideg, rowptr, bsum, ntot);
    k_scan2<<<1, 64, 0, stream>>>(bsum, nb);
    k_scan3<<<nb, 256, 0, stream>>>(rowptr, bsum, ntot, Etot);
    k_dinv_i<<<gs(cN0 + cN1 + cN2), TPB, 0, stream>>>(ideg, dinv, cN0 + cN1 + cN2);
    k_scatter_all<<<gs(Etot), TPB, 0, stream>>>(d, rowptr, cursor, colsp, valsp,
                                                wcol, dinv, Etot);

    // ---- generic Tx recurrence ----
    auto run_sprops = [&](const float* x, int doffs, int n, int Cs, TxPtrs& txs) {
        const int* rp = rowptr + doffs;
        const float* dv = dinv + doffs;
        auto sprop = [&](const float* src, const float* prev, float* dst, int mode) {
            long long work = (long long)n * (Cs >> 2);
            if (Cs == 4)
                k_sprop_t<4><<<gs(work), TPB, 0, stream>>>(rp, colsp, wcol, dv, src, prev, dst, n, mode);
            else if (Cs == 32)
                k_sprop_t<32><<<gs(work), TPB, 0, stream>>>(rp, colsp, wcol, dv, src, prev, dst, n, mode);
            else
                k_sprop_t<64><<<gs(work), TPB, 0, stream>>>(rp, colsp, wcol, dv, src, prev, dst, n, mode);
        };
        txs.p[0] = x;
        for (int i = 1; i < 6; ++i) txs.p[i] = txbuf + (long long)(i - 1) * 800000;
        sprop(txs.p[0], nullptr, (float*)txs.p[1], 0);
        for (int k = 2; k < 6; ++k)
            sprop(txs.p[k - 1], txs.p[k - 2], (float*)txs.p[k], 1);
    };

    // ---- layer 0: pos4 (N0x4, CIN=3) -> bufOut (N0x32); pool0 -> bufPool ----
    {
        TxPtrs txs;
        run_sprops(pos4, doff0, cN0, 4, txs);
        k_outgemm0<<<gs((long long)cN0 * 8), TPB, 0, stream>>>(bufOut, txs, W0, b0, cN0);
        k_spool4_t<32><<<gs((long long)cN1 * 8), TPB, 0, stream>>>(
            rowptr + doffp0, colsp, valsp, bufOut, bufPool, cN1);
    }

    // ---- layer 1: bufPool (N1x32) -> part[0..2] (each N1x64); pool1 fused ----
    {
        TxPtrs txs;
        run_sprops(bufPool, doff1, cN1, 32, txs);
        const int pstride = cN1 * 64;  // 1600000
        k_outsplit_nt<32, 64, 3, 5><<<gs((long long)(cN1 / 5) * 16 * 3), TPB, 0, stream>>>(
            part, txs, W1, cN1, pstride);
        k_pool_f<64, 3><<<gs((long long)cN2 * 16), TPB, 0, stream>>>(
            rowptr + doffp1, colsp, valsp, part, b1, bufPool, cN2, pstride);
    }

    // ---- layer 2: bufPool (N2x64) -> part[0..5] (each N2x128); head fused ----
    {
        TxPtrs txs;
        run_sprops(bufPool, doff2, cN2, 64, txs);
        const int pstride = cN2 * 128;  // 800000
        k_outsplit_nt<64, 128, 6, 5><<<gs((long long)(cN2 / 5) * 32 * 6), TPB, 0, stream>>>(
            part, txs, W2, cN2, pstride);
        k_linear_partial_f<<<NBLK, TPB, 0, stream>>>(
            lw, (const float4*)part, b2, lpart, cN2 * 128 / 4, cN2 * 128, NBLK);
        k_linear_final<<<1, 640, 0, stream>>>(lpart, lb, outZ, NBLK);
    }
}

// Round 8
// 347.121 us; speedup vs baseline: 1.2822x; 1.2822x over previous
//
#include <hip/hip_runtime.h>

// ChebNet classifier: 3x ChebConv(K=6) + 2x sparse pool + linear head.
// R7 post-mortem: NT=5 outsplit SPILLED (VGPR capped at 64, acc/xv arrays
//     to scratch -> 180MB write / 98MB fetch of pure spill traffic, 105us).
// R8: NT=2 (live regs ~32) + __launch_bounds__(256,4) -- no spill, still
//     1.67x fewer vmem instrs than R6's NT=1 (51us version).

#define TPB 256

static inline int gs(long long n) { return (int)((n + TPB - 1) / TPB); }

struct Desc5 {
    const int* rows[5];
    const int* cols[5];
    const float* vals[5];
    int eoff[6];
    int doff[5];
};

struct TxPtrs { const float* p[6]; };

// ---------- batched CSR build ----------

__global__ void k_count_all(Desc5 d, int* __restrict__ cnt, int Etot) {
    int e = blockIdx.x * blockDim.x + threadIdx.x;
    if (e >= Etot) return;
    int s = 0;
    while (e >= d.eoff[s + 1]) ++s;
    int le = e - d.eoff[s];
    atomicAdd(&cnt[d.doff[s] + d.rows[s][le]], 1);
}

__global__ void k_scan1(const int* __restrict__ cnt, int* __restrict__ excl,
                        int* __restrict__ bsum, int n) {
    int gid = blockIdx.x * 256 + threadIdx.x;
    int v = (gid < n) ? cnt[gid] : 0;
    int lane = threadIdx.x & 63, wid = threadIdx.x >> 6;
    int s = v;
#pragma unroll
    for (int off = 1; off < 64; off <<= 1) {
        int t = __shfl_up(s, off, 64);
        if (lane >= off) s += t;
    }
    __shared__ int wsum[4];
    if (lane == 63) wsum[wid] = s;
    __syncthreads();
    int add = 0;
    for (int w = 0; w < wid; ++w) add += wsum[w];
    if (gid < n) excl[gid] = add + s - v;
    if (threadIdx.x == 255) bsum[blockIdx.x] = add + s;
}

__global__ void k_scan2(int* __restrict__ bsum, int nb) {
    int lane = threadIdx.x;  // blockDim = 64
    int carry = 0;
    for (int base = 0; base < nb; base += 64) {
        int i = base + lane;
        int v = (i < nb) ? bsum[i] : 0;
        int s = v;
#pragma unroll
        for (int off = 1; off < 64; off <<= 1) {
            int t = __shfl_up(s, off, 64);
            if (lane >= off) s += t;
        }
        if (i < nb) bsum[i] = carry + s - v;
        carry += __shfl(s, 63, 64);
    }
}

__global__ void k_scan3(int* __restrict__ rowptr, const int* __restrict__ bsum,
                        int n, int E) {
    int gid = blockIdx.x * 256 + threadIdx.x;
    if (gid < n) rowptr[gid] += bsum[blockIdx.x];
    if (gid == 0) rowptr[n] = E;
}

__global__ void k_dinv_i(const int* __restrict__ cnt, float* __restrict__ dinv, int n) {
    int i = blockIdx.x * blockDim.x + threadIdx.x;
    if (i < n) {
        int d = cnt[i];
        dinv[i] = d > 0 ? 1.0f / sqrtf((float)d) : 0.f;
    }
}

// scatter edges into CSR slots; for graph segments (s<3) also emit
// wcol[pos] = dinv[col] (dinv_i has already run).
__global__ void k_scatter_all(Desc5 d, const int* __restrict__ rowptr,
                              int* __restrict__ cursor, int* __restrict__ colsp,
                              float* __restrict__ valsp, float* __restrict__ wcol,
                              const float* __restrict__ dinv, int Etot) {
    int e = blockIdx.x * blockDim.x + threadIdx.x;
    if (e >= Etot) return;
    int s = 0;
    while (e >= d.eoff[s + 1]) ++s;
    int le = e - d.eoff[s];
    int gr = d.doff[s] + d.rows[s][le];
    int pos = rowptr[gr] + atomicAdd(&cursor[gr], 1);
    int cv = d.cols[s][le];
    colsp[pos] = cv;
    if (s < 3) wcol[pos] = dinv[d.doff[s] + cv];
    else       valsp[pos] = d.vals[s][le];
}

// pos (N0 x 3) -> pos4 (N0 x 4, w = 0)
__global__ void k_pad4(const float* __restrict__ pos, float4* __restrict__ pos4, int n) {
    int i = blockIdx.x * blockDim.x + threadIdx.x;
    if (i < n) pos4[i] = make_float4(pos[3 * i], pos[3 * i + 1], pos[3 * i + 2], 0.f);
}

// ---------- gather SpMV (Cheb prop) ----------
// acc = sum_j wcol_j * src[col_j]; prop = -dinv[r]*acc
// mode 0: dst = prop ; mode 1: dst = 2*prop - prev

template <int C>
__global__ void k_sprop_t(const int* __restrict__ rowptr, const int* __restrict__ colsp,
                          const float* __restrict__ wcol, const float* __restrict__ dinv,
                          const float* __restrict__ src, const float* __restrict__ prev,
                          float* __restrict__ dst, int n, int mode) {
    constexpr int C4 = C / 4;
    int idx = blockIdx.x * blockDim.x + threadIdx.x;
    if (idx >= n * C4) return;
    int r = idx / C4, c4 = (idx - r * C4) * 4;
    int s0 = rowptr[r], s1 = rowptr[r + 1];
    float4 acca = make_float4(0.f, 0.f, 0.f, 0.f);
    float4 accb = make_float4(0.f, 0.f, 0.f, 0.f);
    int j = s0;
    for (; j + 2 <= s1; j += 2) {
        int ca = colsp[j], cb = colsp[j + 1];
        float wa = wcol[j], wb = wcol[j + 1];
        float4 sa = *(const float4*)(src + (long long)ca * C + c4);
        float4 sb = *(const float4*)(src + (long long)cb * C + c4);
        acca.x += wa * sa.x; acca.y += wa * sa.y; acca.z += wa * sa.z; acca.w += wa * sa.w;
        accb.x += wb * sb.x; accb.y += wb * sb.y; accb.z += wb * sb.z; accb.w += wb * sb.w;
    }
    if (j < s1) {
        int c = colsp[j];
        float w = wcol[j];
        float4 s = *(const float4*)(src + (long long)c * C + c4);
        acca.x += w * s.x; acca.y += w * s.y; acca.z += w * s.z; acca.w += w * s.w;
    }
    acca.x += accb.x; acca.y += accb.y; acca.z += accb.z; acca.w += accb.w;
    float m = -dinv[r];
    long long o = (long long)r * C + c4;
    float4 out;
    if (mode) {
        float4 p = *(const float4*)(prev + o);
        out.x = 2.f * m * acca.x - p.x; out.y = 2.f * m * acca.y - p.y;
        out.z = 2.f * m * acca.z - p.z; out.w = 2.f * m * acca.w - p.w;
    } else {
        out.x = m * acca.x; out.y = m * acca.y; out.z = m * acca.z; out.w = m * acca.w;
    }
    *(float4*)(dst + o) = out;
}

// ---------- pool0: out[r] = sum_j vals_j * relu(x[col_j]) ----------

template <int C>
__global__ void k_spool4_t(const int* __restrict__ rowptr, const int* __restrict__ colsp,
                           const float* __restrict__ valsp, const float* __restrict__ x,
                           float* __restrict__ out, int n) {
    constexpr int C4 = C / 4;
    int idx = blockIdx.x * blockDim.x + threadIdx.x;
    if (idx >= n * C4) return;
    int r = idx / C4, c4 = (idx - r * C4) * 4;
    int s0 = rowptr[r], s1 = rowptr[r + 1];
    float4 acca = make_float4(0.f, 0.f, 0.f, 0.f);
    float4 accb = make_float4(0.f, 0.f, 0.f, 0.f);
    int j = s0;
    for (; j + 2 <= s1; j += 2) {
        int ca = colsp[j], cb = colsp[j + 1];
        float va = valsp[j], vb = valsp[j + 1];
        float4 sa = *(const float4*)(x + (long long)ca * C + c4);
        float4 sb = *(const float4*)(x + (long long)cb * C + c4);
        acca.x += va * fmaxf(sa.x, 0.f); acca.y += va * fmaxf(sa.y, 0.f);
        acca.z += va * fmaxf(sa.z, 0.f); acca.w += va * fmaxf(sa.w, 0.f);
        accb.x += vb * fmaxf(sb.x, 0.f); accb.y += vb * fmaxf(sb.y, 0.f);
        accb.z += vb * fmaxf(sb.z, 0.f); accb.w += vb * fmaxf(sb.w, 0.f);
    }
    if (j < s1) {
        int c = colsp[j];
        float v = valsp[j];
        float4 s = *(const float4*)(x + (long long)c * C + c4);
        acca.x += v * fmaxf(s.x, 0.f); acca.y += v * fmaxf(s.y, 0.f);
        acca.z += v * fmaxf(s.z, 0.f); acca.w += v * fmaxf(s.w, 0.f);
    }
    acca.x += accb.x; acca.y += accb.y; acca.z += accb.z; acca.w += accb.w;
    *(float4*)(out + (long long)r * C + c4) = acca;
}

// ---------- pool1 fused with layer-1 partial reduce + bias + relu ----------

template <int C, int KSPLIT>
__global__ void k_pool_f(const int* __restrict__ rowptr, const int* __restrict__ colsp,
                         const float* __restrict__ valsp, const float* __restrict__ part,
                         const float* __restrict__ bias, float* __restrict__ out,
                         int n, int partStride) {
    constexpr int C4 = C / 4;
    int idx = blockIdx.x * blockDim.x + threadIdx.x;
    if (idx >= n * C4) return;
    int r = idx / C4, c4 = (idx - r * C4) * 4;
    int s0 = rowptr[r], s1 = rowptr[r + 1];
    float4 bb = *(const float4*)(bias + c4);
    float4 acc = make_float4(0.f, 0.f, 0.f, 0.f);
    for (int j = s0; j < s1; ++j) {
        int c = colsp[j];
        float v = valsp[j];
        float4 x = bb;
#pragma unroll
        for (int s = 0; s < KSPLIT; ++s) {
            float4 p = *(const float4*)(part + (long long)s * partStride + (long long)c * C + c4);
            x.x += p.x; x.y += p.y; x.z += p.z; x.w += p.w;
        }
        acc.x += v * fmaxf(x.x, 0.f); acc.y += v * fmaxf(x.y, 0.f);
        acc.z += v * fmaxf(x.z, 0.f); acc.w += v * fmaxf(x.w, 0.f);
    }
    *(float4*)(out + (long long)r * C + c4) = acc;
}

// ---------- layer-0 direct out-GEMM (CIN=3 stride 4, COUT=32) ----------

__global__ void k_outgemm0(float* __restrict__ out, TxPtrs txs,
                           const float* __restrict__ W, const float* __restrict__ b,
                           int n) {
    int idx = blockIdx.x * blockDim.x + threadIdx.x;
    if (idx >= n * 8) return;
    int node = idx >> 3, co = (idx & 7) * 4;
    float4 acc = *(const float4*)(b + co);
#pragma unroll
    for (int k = 0; k < 6; ++k) {
        float4 xv = ((const float4*)txs.p[k])[node];
        const float* Wk = W + k * 96 + co;
        float4 w0 = *(const float4*)(Wk);
        float4 w1 = *(const float4*)(Wk + 32);
        float4 w2 = *(const float4*)(Wk + 64);
        acc.x += xv.x * w0.x + xv.y * w1.x + xv.z * w2.x;
        acc.y += xv.x * w0.y + xv.y * w1.y + xv.z * w2.y;
        acc.z += xv.x * w0.z + xv.y * w1.z + xv.z * w2.z;
        acc.w += xv.x * w0.w + xv.y * w1.w + xv.z * w2.w;
    }
    *(float4*)(out + (long long)node * 32 + co) = acc;
}

// ---------- node-tiled k-split out-GEMM (NT=2, no spill) ----------
// Thread computes NT nodes x 4 cols for KPER k-values; per ci4-chunk
// NT+4 loads -> NT*16 FMAs. Requires n % NT == 0.

template <int CIN, int COUT, int KSPLIT, int NT>
__global__ __launch_bounds__(256, 4)
void k_outsplit_nt(float* __restrict__ part, TxPtrs txs,
                   const float* __restrict__ W, int n, int partStride) {
    constexpr int CO4 = COUT / 4;
    constexpr int KPER = 6 / KSPLIT;
    int ntile = n / NT;
    int per = ntile * CO4;
    int idx = blockIdx.x * blockDim.x + threadIdx.x;
    if (idx >= per * KSPLIT) return;
    int s = idx / per, t = idx - s * per;
    int tile = t / CO4, co = (t - tile * CO4) * 4;
    int node0 = tile * NT;
    float4 acc[NT];
#pragma unroll
    for (int i = 0; i < NT; ++i) acc[i] = make_float4(0.f, 0.f, 0.f, 0.f);
#pragma unroll
    for (int kk = 0; kk < KPER; ++kk) {
        int k = s * KPER + kk;
        const float* xb = txs.p[k] + (long long)node0 * CIN;
        const float* Wk = W + (long long)k * CIN * COUT + co;
#pragma unroll
        for (int c4 = 0; c4 < CIN / 4; ++c4) {
            float4 xv[NT];
#pragma unroll
            for (int i = 0; i < NT; ++i)
                xv[i] = *(const float4*)(xb + (long long)i * CIN + c4 * 4);
            const float* Wr = Wk + c4 * 4 * COUT;
            float4 w0 = *(const float4*)(Wr);
            float4 w1 = *(const float4*)(Wr + COUT);
            float4 w2 = *(const float4*)(Wr + 2 * COUT);
            float4 w3 = *(const float4*)(Wr + 3 * COUT);
#pragma unroll
            for (int i = 0; i < NT; ++i) {
                acc[i].x += xv[i].x * w0.x + xv[i].y * w1.x + xv[i].z * w2.x + xv[i].w * w3.x;
                acc[i].y += xv[i].x * w0.y + xv[i].y * w1.y + xv[i].z * w2.y + xv[i].w * w3.y;
                acc[i].z += xv[i].x * w0.z + xv[i].y * w1.z + xv[i].z * w2.z + xv[i].w * w3.z;
                acc[i].w += xv[i].x * w0.w + xv[i].y * w1.w + xv[i].z * w2.w + xv[i].w * w3.w;
            }
        }
    }
    float* op = part + (long long)s * partStride + (long long)node0 * COUT + co;
#pragma unroll
    for (int i = 0; i < NT; ++i)
        *(float4*)(op + (long long)i * COUT) = acc[i];
}

// ---------- linear head, fused with layer-2 partial reduce + bias ----------

__global__ void k_linear_partial_f(const float* __restrict__ lw,
                                   const float4* __restrict__ part,
                                   const float* __restrict__ b2,
                                   float* __restrict__ partials,
                                   int len4, int len, int nblk) {
    float acc[10];
#pragma unroll
    for (int j = 0; j < 10; ++j) acc[j] = 0.f;
    const float4* b2v = (const float4*)b2;
    for (int i = blockIdx.x * blockDim.x + threadIdx.x; i < len4;
         i += gridDim.x * blockDim.x) {
        float4 xv = b2v[i & 31];
#pragma unroll
        for (int s = 0; s < 6; ++s) {
            float4 p = part[s * 200000 + i];
            xv.x += p.x; xv.y += p.y; xv.z += p.z; xv.w += p.w;
        }
#pragma unroll
        for (int j = 0; j < 10; ++j) {
            float4 wv = *(const float4*)(lw + (long long)j * len + i * 4);
            acc[j] += xv.x * wv.x + xv.y * wv.y + xv.z * wv.z + xv.w * wv.w;
        }
    }
    __shared__ float lds[4][10];
    int wid = threadIdx.x >> 6, lane = threadIdx.x & 63;
#pragma unroll
    for (int j = 0; j < 10; ++j) {
        float v = acc[j];
        for (int off = 32; off > 0; off >>= 1) v += __shfl_down(v, off, 64);
        if (lane == 0) lds[wid][j] = v;
    }
    __syncthreads();
    if (threadIdx.x < 10) {
        float s = lds[0][threadIdx.x] + lds[1][threadIdx.x] +
                  lds[2][threadIdx.x] + lds[3][threadIdx.x];
        partials[threadIdx.x * nblk + blockIdx.x] = s;
    }
}

__global__ void k_linear_final(const float* __restrict__ partials,
                               const float* __restrict__ lb,
                               float* __restrict__ out, int nblk) {
    int j = threadIdx.x >> 6, lane = threadIdx.x & 63;
    float v = 0.f;
    for (int b = lane; b < nblk; b += 64) v += partials[j * nblk + b];
    for (int off = 32; off > 0; off >>= 1) v += __shfl_down(v, off, 64);
    if (lane == 0) out[j] = lb[j] + v;
}

extern "C" void kernel_launch(void* const* d_in, const int* in_sizes, int n_in,
                              void* d_out, int out_size, void* d_ws, size_t ws_size,
                              hipStream_t stream) {
    const int cN0 = 100000, cN1 = 25000, cN2 = 6250;
    const int cE0 = 600000, cE1 = 150000, cE2 = 40000;
    const int NBLK = 512;

    const float* pos = (const float*)d_in[0];
    const int*   ei0 = (const int*)d_in[1];
    const int*   ei1 = (const int*)d_in[2];
    const int*   ei2 = (const int*)d_in[3];
    const int*   d0r = (const int*)d_in[4];
    const int*   d0c = (const int*)d_in[5];
    const float* d0v = (const float*)d_in[6];
    const int*   d1r = (const int*)d_in[7];
    const int*   d1c = (const int*)d_in[8];
    const float* d1v = (const float*)d_in[9];
    const float* W0  = (const float*)d_in[10];
    const float* b0  = (const float*)d_in[11];
    const float* W1  = (const float*)d_in[12];
    const float* b1  = (const float*)d_in[13];
    const float* W2  = (const float*)d_in[14];
    const float* b2  = (const float*)d_in[15];
    const float* lw  = (const float*)d_in[16];
    const float* lb  = (const float*)d_in[17];
    float* outZ = (float*)d_out;

    // concatenated row space: g0 g1 g2 p0 p1
    const int ntot = cN0 + cN1 + cN2 + cN1 + cN2;          // 162500
    const int Etot = cE0 + cE1 + cE2 + cN0 + cN1;          // 915000
    const int Eg   = cE0 + cE1 + cE2;                      // 790000 (graph edges)
    const int doff0 = 0, doff1 = cN0, doff2 = cN0 + cN1,
              doffp0 = doff2 + cN2, doffp1 = doffp0 + cN1;

    // workspace layout (4B units); all float4 bases 16B-aligned
    int*   iws    = (int*)d_ws;
    int*   ideg   = iws;                         // 162500
    int*   cursor = ideg + 162500;               // 162500 (adjacent: one memset)
    int*   rowptr = cursor + 162500;             // 162504
    int*   bsum   = rowptr + 162504;             // 704
    float* dinv   = (float*)(bsum + 704);        // 131256
    int*   colsp  = (int*)(dinv + 131256);       // 915000
    float* valsp  = (float*)(colsp + 915000);    // 915000
    float* wcol   = valsp + 915000;              // 790000
    float* pos4   = wcol + 790000;               // 400000
    float* txbuf  = pos4 + 400000;               // 5 x 800000
    float* part   = txbuf + 5 * 800000;          // 4800000
    float* bufOut = part + 4800000;              // 3200000
    float* bufPool= bufOut + 3200000;            // 800000
    float* lpart  = bufPool + 800000;            // 5120

    // ---- independent prep ----
    k_pad4<<<gs(cN0), TPB, 0, stream>>>(pos, (float4*)pos4, cN0);

    // ---- batched CSR build ----
    Desc5 d;
    d.rows[0] = ei0;        d.cols[0] = ei0 + cE0; d.vals[0] = nullptr;
    d.rows[1] = ei1;        d.cols[1] = ei1 + cE1; d.vals[1] = nullptr;
    d.rows[2] = ei2;        d.cols[2] = ei2 + cE2; d.vals[2] = nullptr;
    d.rows[3] = d0r;        d.cols[3] = d0c;       d.vals[3] = d0v;
    d.rows[4] = d1r;        d.cols[4] = d1c;       d.vals[4] = d1v;
    d.eoff[0] = 0;
    d.eoff[1] = cE0;
    d.eoff[2] = cE0 + cE1;
    d.eoff[3] = Eg;
    d.eoff[4] = Eg + cN0;
    d.eoff[5] = Etot;
    d.doff[0] = doff0; d.doff[1] = doff1; d.doff[2] = doff2;
    d.doff[3] = doffp0; d.doff[4] = doffp1;

    hipMemsetAsync(ideg, 0, (size_t)(162500 + 162500) * 4, stream);
    k_count_all<<<gs(Etot), TPB, 0, stream>>>(d, ideg, Etot);
    int nb = (ntot + 255) / 256;
    k_scan1<<<nb, 256, 0, stream>>>(ideg, rowptr, bsum, ntot);
    k_scan2<<<1, 64, 0, stream>>>(bsum, nb);
    k_scan3<<<nb, 256, 0, stream>>>(rowptr, bsum, ntot, Etot);
    k_dinv_i<<<gs(cN0 + cN1 + cN2), TPB, 0, stream>>>(ideg, dinv, cN0 + cN1 + cN2);
    k_scatter_all<<<gs(Etot), TPB, 0, stream>>>(d, rowptr, cursor, colsp, valsp,
                                                wcol, dinv, Etot);

    // ---- generic Tx recurrence ----
    auto run_sprops = [&](const float* x, int doffs, int n, int Cs, TxPtrs& txs) {
        const int* rp = rowptr + doffs;
        const float* dv = dinv + doffs;
        auto sprop = [&](const float* src, const float* prev, float* dst, int mode) {
            long long work = (long long)n * (Cs >> 2);
            if (Cs == 4)
                k_sprop_t<4><<<gs(work), TPB, 0, stream>>>(rp, colsp, wcol, dv, src, prev, dst, n, mode);
            else if (Cs == 32)
                k_sprop_t<32><<<gs(work), TPB, 0, stream>>>(rp, colsp, wcol, dv, src, prev, dst, n, mode);
            else
                k_sprop_t<64><<<gs(work), TPB, 0, stream>>>(rp, colsp, wcol, dv, src, prev, dst, n, mode);
        };
        txs.p[0] = x;
        for (int i = 1; i < 6; ++i) txs.p[i] = txbuf + (long long)(i - 1) * 800000;
        sprop(txs.p[0], nullptr, (float*)txs.p[1], 0);
        for (int k = 2; k < 6; ++k)
            sprop(txs.p[k - 1], txs.p[k - 2], (float*)txs.p[k], 1);
    };

    // ---- layer 0: pos4 (N0x4, CIN=3) -> bufOut (N0x32); pool0 -> bufPool ----
    {
        TxPtrs txs;
        run_sprops(pos4, doff0, cN0, 4, txs);
        k_outgemm0<<<gs((long long)cN0 * 8), TPB, 0, stream>>>(bufOut, txs, W0, b0, cN0);
        k_spool4_t<32><<<gs((long long)cN1 * 8), TPB, 0, stream>>>(
            rowptr + doffp0, colsp, valsp, bufOut, bufPool, cN1);
    }

    // ---- layer 1: bufPool (N1x32) -> part[0..2] (each N1x64); pool1 fused ----
    {
        TxPtrs txs;
        run_sprops(bufPool, doff1, cN1, 32, txs);
        const int pstride = cN1 * 64;  // 1600000
        k_outsplit_nt<32, 64, 3, 2><<<gs((long long)(cN1 / 2) * 16 * 3), TPB, 0, stream>>>(
            part, txs, W1, cN1, pstride);
        k_pool_f<64, 3><<<gs((long long)cN2 * 16), TPB, 0, stream>>>(
            rowptr + doffp1, colsp, valsp, part, b1, bufPool, cN2, pstride);
    }

    // ---- layer 2: bufPool (N2x64) -> part[0..5] (each N2x128); head fused ----
    {
        TxPtrs txs;
        run_sprops(bufPool, doff2, cN2, 64, txs);
        const int pstride = cN2 * 128;  // 800000
        k_outsplit_nt<64, 128, 6, 2><<<gs((long long)(cN2 / 2) * 32 * 6), TPB, 0, stream>>>(
            part, txs, W2, cN2, pstride);
        k_linear_partial_f<<<NBLK, TPB, 0, stream>>>(
            lw, (const float4*)part, b2, lpart, cN2 * 128 / 4, cN2 * 128, NBLK);
        k_linear_final<<<1, 640, 0, stream>>>(lpart, lb, outZ, NBLK);
    }
}

// Round 9
// 346.551 us; speedup vs baseline: 1.2844x; 1.0016x over previous
//
#include <hip/hip_runtime.h>

// ChebNet classifier: 3x ChebConv(K=6) + 2x sparse pool + linear head.
// R8 post-mortem: scatter was 57us -- two 4B scattered writes/edge = 93MB
//     of dirty sectors (12x amplification) + rowptr gather + cursor atomic.
// R9: (a) pack (col,weight) into ONE int2 record -> one 8B scattered write,
//     consumers load one int2/edge instead of two 4B loads; (b) cursor
//     pre-init in scan3 (no rowptr gather in scatter); (c) dinv fused
//     into scan1.

#define TPB 256

static inline int gs(long long n) { return (int)((n + TPB - 1) / TPB); }

struct Desc5 {
    const int* rows[5];
    const int* cols[5];
    const float* vals[5];
    int eoff[6];
    int doff[5];
};

struct TxPtrs { const float* p[6]; };

// ---------- batched CSR build ----------

__global__ void k_count_all(Desc5 d, int* __restrict__ cnt, int Etot) {
    int e = blockIdx.x * blockDim.x + threadIdx.x;
    if (e >= Etot) return;
    int s = 0;
    while (e >= d.eoff[s + 1]) ++s;
    int le = e - d.eoff[s];
    atomicAdd(&cnt[d.doff[s] + d.rows[s][le]], 1);
}

// per-block exclusive scan; also emits dinv for the first ndinv rows
__global__ void k_scan1(const int* __restrict__ cnt, int* __restrict__ excl,
                        int* __restrict__ bsum, float* __restrict__ dinv,
                        int ndinv, int n) {
    int gid = blockIdx.x * 256 + threadIdx.x;
    int v = (gid < n) ? cnt[gid] : 0;
    if (gid < ndinv) dinv[gid] = v > 0 ? 1.0f / sqrtf((float)v) : 0.f;
    int lane = threadIdx.x & 63, wid = threadIdx.x >> 6;
    int s = v;
#pragma unroll
    for (int off = 1; off < 64; off <<= 1) {
        int t = __shfl_up(s, off, 64);
        if (lane >= off) s += t;
    }
    __shared__ int wsum[4];
    if (lane == 63) wsum[wid] = s;
    __syncthreads();
    int add = 0;
    for (int w = 0; w < wid; ++w) add += wsum[w];
    if (gid < n) excl[gid] = add + s - v;
    if (threadIdx.x == 255) bsum[blockIdx.x] = add + s;
}

__global__ void k_scan2(int* __restrict__ bsum, int nb) {
    int lane = threadIdx.x;  // blockDim = 64
    int carry = 0;
    for (int base = 0; base < nb; base += 64) {
        int i = base + lane;
        int v = (i < nb) ? bsum[i] : 0;
        int s = v;
#pragma unroll
        for (int off = 1; off < 64; off <<= 1) {
            int t = __shfl_up(s, off, 64);
            if (lane >= off) s += t;
        }
        if (i < nb) bsum[i] = carry + s - v;
        carry += __shfl(s, 63, 64);
    }
}

// finalize rowptr and initialize cursor = rowptr (scatter atomics run on cursor)
__global__ void k_scan3(int* __restrict__ rowptr, int* __restrict__ cursor,
                        const int* __restrict__ bsum, int n, int E) {
    int gid = blockIdx.x * 256 + threadIdx.x;
    if (gid < n) {
        int v = rowptr[gid] + bsum[blockIdx.x];
        rowptr[gid] = v;
        cursor[gid] = v;
    }
    if (gid == 0) rowptr[n] = E;
}

// one 8B record per edge: (col, weight-or-val bits)
__global__ void k_scatter_all(Desc5 d, int* __restrict__ cursor,
                              int2* __restrict__ rec,
                              const float* __restrict__ dinv, int Etot) {
    int e = blockIdx.x * blockDim.x + threadIdx.x;
    if (e >= Etot) return;
    int s = 0;
    while (e >= d.eoff[s + 1]) ++s;
    int le = e - d.eoff[s];
    int gr = d.doff[s] + d.rows[s][le];
    int pos = atomicAdd(&cursor[gr], 1);
    int cv = d.cols[s][le];
    float wv = (s < 3) ? dinv[d.doff[s] + cv] : d.vals[s][le];
    rec[pos] = make_int2(cv, __float_as_int(wv));
}

// pos (N0 x 3) -> pos4 (N0 x 4, w = 0)
__global__ void k_pad4(const float* __restrict__ pos, float4* __restrict__ pos4, int n) {
    int i = blockIdx.x * blockDim.x + threadIdx.x;
    if (i < n) pos4[i] = make_float4(pos[3 * i], pos[3 * i + 1], pos[3 * i + 2], 0.f);
}

// ---------- gather SpMV (Cheb prop) ----------
// acc = sum_j w_j * src[col_j]; prop = -dinv[r]*acc
// mode 0: dst = prop ; mode 1: dst = 2*prop - prev

template <int C>
__global__ void k_sprop_t(const int* __restrict__ rowptr, const int2* __restrict__ rec,
                          const float* __restrict__ dinv, const float* __restrict__ src,
                          const float* __restrict__ prev, float* __restrict__ dst,
                          int n, int mode) {
    constexpr int C4 = C / 4;
    int idx = blockIdx.x * blockDim.x + threadIdx.x;
    if (idx >= n * C4) return;
    int r = idx / C4, c4 = (idx - r * C4) * 4;
    int s0 = rowptr[r], s1 = rowptr[r + 1];
    float4 acca = make_float4(0.f, 0.f, 0.f, 0.f);
    float4 accb = make_float4(0.f, 0.f, 0.f, 0.f);
    int j = s0;
    for (; j + 2 <= s1; j += 2) {
        int2 ra = rec[j], rb = rec[j + 1];
        float wa = __int_as_float(ra.y), wb = __int_as_float(rb.y);
        float4 sa = *(const float4*)(src + (long long)ra.x * C + c4);
        float4 sb = *(const float4*)(src + (long long)rb.x * C + c4);
        acca.x += wa * sa.x; acca.y += wa * sa.y; acca.z += wa * sa.z; acca.w += wa * sa.w;
        accb.x += wb * sb.x; accb.y += wb * sb.y; accb.z += wb * sb.z; accb.w += wb * sb.w;
    }
    if (j < s1) {
        int2 rr = rec[j];
        float w = __int_as_float(rr.y);
        float4 s = *(const float4*)(src + (long long)rr.x * C + c4);
        acca.x += w * s.x; acca.y += w * s.y; acca.z += w * s.z; acca.w += w * s.w;
    }
    acca.x += accb.x; acca.y += accb.y; acca.z += accb.z; acca.w += accb.w;
    float m = -dinv[r];
    long long o = (long long)r * C + c4;
    float4 out;
    if (mode) {
        float4 p = *(const float4*)(prev + o);
        out.x = 2.f * m * acca.x - p.x; out.y = 2.f * m * acca.y - p.y;
        out.z = 2.f * m * acca.z - p.z; out.w = 2.f * m * acca.w - p.w;
    } else {
        out.x = m * acca.x; out.y = m * acca.y; out.z = m * acca.z; out.w = m * acca.w;
    }
    *(float4*)(dst + o) = out;
}

// ---------- pool0: out[r] = sum_j val_j * relu(x[col_j]) ----------

template <int C>
__global__ void k_spool4_t(const int* __restrict__ rowptr, const int2* __restrict__ rec,
                           const float* __restrict__ x, float* __restrict__ out, int n) {
    constexpr int C4 = C / 4;
    int idx = blockIdx.x * blockDim.x + threadIdx.x;
    if (idx >= n * C4) return;
    int r = idx / C4, c4 = (idx - r * C4) * 4;
    int s0 = rowptr[r], s1 = rowptr[r + 1];
    float4 acca = make_float4(0.f, 0.f, 0.f, 0.f);
    float4 accb = make_float4(0.f, 0.f, 0.f, 0.f);
    int j = s0;
    for (; j + 2 <= s1; j += 2) {
        int2 ra = rec[j], rb = rec[j + 1];
        float va = __int_as_float(ra.y), vb = __int_as_float(rb.y);
        float4 sa = *(const float4*)(x + (long long)ra.x * C + c4);
        float4 sb = *(const float4*)(x + (long long)rb.x * C + c4);
        acca.x += va * fmaxf(sa.x, 0.f); acca.y += va * fmaxf(sa.y, 0.f);
        acca.z += va * fmaxf(sa.z, 0.f); acca.w += va * fmaxf(sa.w, 0.f);
        accb.x += vb * fmaxf(sb.x, 0.f); accb.y += vb * fmaxf(sb.y, 0.f);
        accb.z += vb * fmaxf(sb.z, 0.f); accb.w += vb * fmaxf(sb.w, 0.f);
    }
    if (j < s1) {
        int2 rr = rec[j];
        float v = __int_as_float(rr.y);
        float4 s = *(const float4*)(x + (long long)rr.x * C + c4);
        acca.x += v * fmaxf(s.x, 0.f); acca.y += v * fmaxf(s.y, 0.f);
        acca.z += v * fmaxf(s.z, 0.f); acca.w += v * fmaxf(s.w, 0.f);
    }
    acca.x += accb.x; acca.y += accb.y; acca.z += accb.z; acca.w += accb.w;
    *(float4*)(out + (long long)r * C + c4) = acca;
}

// ---------- pool1 fused with layer-1 partial reduce + bias + relu ----------

template <int C, int KSPLIT>
__global__ void k_pool_f(const int* __restrict__ rowptr, const int2* __restrict__ rec,
                         const float* __restrict__ part, const float* __restrict__ bias,
                         float* __restrict__ out, int n, int partStride) {
    constexpr int C4 = C / 4;
    int idx = blockIdx.x * blockDim.x + threadIdx.x;
    if (idx >= n * C4) return;
    int r = idx / C4, c4 = (idx - r * C4) * 4;
    int s0 = rowptr[r], s1 = rowptr[r + 1];
    float4 bb = *(const float4*)(bias + c4);
    float4 acc = make_float4(0.f, 0.f, 0.f, 0.f);
    for (int j = s0; j < s1; ++j) {
        int2 rr = rec[j];
        float v = __int_as_float(rr.y);
        float4 x = bb;
#pragma unroll
        for (int s = 0; s < KSPLIT; ++s) {
            float4 p = *(const float4*)(part + (long long)s * partStride + (long long)rr.x * C + c4);
            x.x += p.x; x.y += p.y; x.z += p.z; x.w += p.w;
        }
        acc.x += v * fmaxf(x.x, 0.f); acc.y += v * fmaxf(x.y, 0.f);
        acc.z += v * fmaxf(x.z, 0.f); acc.w += v * fmaxf(x.w, 0.f);
    }
    *(float4*)(out + (long long)r * C + c4) = acc;
}

// ---------- layer-0 direct out-GEMM (CIN=3 stride 4, COUT=32) ----------

__global__ void k_outgemm0(float* __restrict__ out, TxPtrs txs,
                           const float* __restrict__ W, const float* __restrict__ b,
                           int n) {
    int idx = blockIdx.x * blockDim.x + threadIdx.x;
    if (idx >= n * 8) return;
    int node = idx >> 3, co = (idx & 7) * 4;
    float4 acc = *(const float4*)(b + co);
#pragma unroll
    for (int k = 0; k < 6; ++k) {
        float4 xv = ((const float4*)txs.p[k])[node];
        const float* Wk = W + k * 96 + co;
        float4 w0 = *(const float4*)(Wk);
        float4 w1 = *(const float4*)(Wk + 32);
        float4 w2 = *(const float4*)(Wk + 64);
        acc.x += xv.x * w0.x + xv.y * w1.x + xv.z * w2.x;
        acc.y += xv.x * w0.y + xv.y * w1.y + xv.z * w2.y;
        acc.z += xv.x * w0.z + xv.y * w1.z + xv.z * w2.z;
        acc.w += xv.x * w0.w + xv.y * w1.w + xv.z * w2.w;
    }
    *(float4*)(out + (long long)node * 32 + co) = acc;
}

// ---------- node-tiled k-split out-GEMM (NT=2, no spill) ----------

template <int CIN, int COUT, int KSPLIT, int NT>
__global__ __launch_bounds__(256, 4)
void k_outsplit_nt(float* __restrict__ part, TxPtrs txs,
                   const float* __restrict__ W, int n, int partStride) {
    constexpr int CO4 = COUT / 4;
    constexpr int KPER = 6 / KSPLIT;
    int ntile = n / NT;
    int per = ntile * CO4;
    int idx = blockIdx.x * blockDim.x + threadIdx.x;
    if (idx >= per * KSPLIT) return;
    int s = idx / per, t = idx - s * per;
    int tile = t / CO4, co = (t - tile * CO4) * 4;
    int node0 = tile * NT;
    float4 acc[NT];
#pragma unroll
    for (int i = 0; i < NT; ++i) acc[i] = make_float4(0.f, 0.f, 0.f, 0.f);
#pragma unroll
    for (int kk = 0; kk < KPER; ++kk) {
        int k = s * KPER + kk;
        const float* xb = txs.p[k] + (long long)node0 * CIN;
        const float* Wk = W + (long long)k * CIN * COUT + co;
#pragma unroll
        for (int c4 = 0; c4 < CIN / 4; ++c4) {
            float4 xv[NT];
#pragma unroll
            for (int i = 0; i < NT; ++i)
                xv[i] = *(const float4*)(xb + (long long)i * CIN + c4 * 4);
            const float* Wr = Wk + c4 * 4 * COUT;
            float4 w0 = *(const float4*)(Wr);
            float4 w1 = *(const float4*)(Wr + COUT);
            float4 w2 = *(const float4*)(Wr + 2 * COUT);
            float4 w3 = *(const float4*)(Wr + 3 * COUT);
#pragma unroll
            for (int i = 0; i < NT; ++i) {
                acc[i].x += xv[i].x * w0.x + xv[i].y * w1.x + xv[i].z * w2.x + xv[i].w * w3.x;
                acc[i].y += xv[i].x * w0.y + xv[i].y * w1.y + xv[i].z * w2.y + xv[i].w * w3.y;
                acc[i].z += xv[i].x * w0.z + xv[i].y * w1.z + xv[i].z * w2.z + xv[i].w * w3.z;
                acc[i].w += xv[i].x * w0.w + xv[i].y * w1.w + xv[i].z * w2.w + xv[i].w * w3.w;
            }
        }
    }
    float* op = part + (long long)s * partStride + (long long)node0 * COUT + co;
#pragma unroll
    for (int i = 0; i < NT; ++i)
        *(float4*)(op + (long long)i * COUT) = acc[i];
}

// ---------- linear head, fused with layer-2 partial reduce + bias ----------

__global__ void k_linear_partial_f(const float* __restrict__ lw,
                                   const float4* __restrict__ part,
                                   const float* __restrict__ b2,
                                   float* __restrict__ partials,
                                   int len4, int len, int nblk) {
    float acc[10];
#pragma unroll
    for (int j = 0; j < 10; ++j) acc[j] = 0.f;
    const float4* b2v = (const float4*)b2;
    for (int i = blockIdx.x * blockDim.x + threadIdx.x; i < len4;
         i += gridDim.x * blockDim.x) {
        float4 xv = b2v[i & 31];
#pragma unroll
        for (int s = 0; s < 6; ++s) {
            float4 p = part[s * 200000 + i];
            xv.x += p.x; xv.y += p.y; xv.z += p.z; xv.w += p.w;
        }
#pragma unroll
        for (int j = 0; j < 10; ++j) {
            float4 wv = *(const float4*)(lw + (long long)j * len + i * 4);
            acc[j] += xv.x * wv.x + xv.y * wv.y + xv.z * wv.z + xv.w * wv.w;
        }
    }
    __shared__ float lds[4][10];
    int wid = threadIdx.x >> 6, lane = threadIdx.x & 63;
#pragma unroll
    for (int j = 0; j < 10; ++j) {
        float v = acc[j];
        for (int off = 32; off > 0; off >>= 1) v += __shfl_down(v, off, 64);
        if (lane == 0) lds[wid][j] = v;
    }
    __syncthreads();
    if (threadIdx.x < 10) {
        float s = lds[0][threadIdx.x] + lds[1][threadIdx.x] +
                  lds[2][threadIdx.x] + lds[3][threadIdx.x];
        partials[threadIdx.x * nblk + blockIdx.x] = s;
    }
}

__global__ void k_linear_final(const float* __restrict__ partials,
                               const float* __restrict__ lb,
                               float* __restrict__ out, int nblk) {
    int j = threadIdx.x >> 6, lane = threadIdx.x & 63;
    float v = 0.f;
    for (int b = lane; b < nblk; b += 64) v += partials[j * nblk + b];
    for (int off = 32; off > 0; off >>= 1) v += __shfl_down(v, off, 64);
    if (lane == 0) out[j] = lb[j] + v;
}

extern "C" void kernel_launch(void* const* d_in, const int* in_sizes, int n_in,
                              void* d_out, int out_size, void* d_ws, size_t ws_size,
                              hipStream_t stream) {
    const int cN0 = 100000, cN1 = 25000, cN2 = 6250;
    const int cE0 = 600000, cE1 = 150000, cE2 = 40000;
    const int NBLK = 512;

    const float* pos = (const float*)d_in[0];
    const int*   ei0 = (const int*)d_in[1];
    const int*   ei1 = (const int*)d_in[2];
    const int*   ei2 = (const int*)d_in[3];
    const int*   d0r = (const int*)d_in[4];
    const int*   d0c = (const int*)d_in[5];
    const float* d0v = (const float*)d_in[6];
    const int*   d1r = (const int*)d_in[7];
    const int*   d1c = (const int*)d_in[8];
    const float* d1v = (const float*)d_in[9];
    const float* W0  = (const float*)d_in[10];
    const float* b0  = (const float*)d_in[11];
    const float* W1  = (const float*)d_in[12];
    const float* b1  = (const float*)d_in[13];
    const float* W2  = (const float*)d_in[14];
    const float* b2  = (const float*)d_in[15];
    const float* lw  = (const float*)d_in[16];
    const float* lb  = (const float*)d_in[17];
    float* outZ = (float*)d_out;

    // concatenated row space: g0 g1 g2 p0 p1
    const int ntot = cN0 + cN1 + cN2 + cN1 + cN2;          // 162500
    const int Etot = cE0 + cE1 + cE2 + cN0 + cN1;          // 915000
    const int Eg   = cE0 + cE1 + cE2;                      // 790000
    const int ndinv = cN0 + cN1 + cN2;                     // 131250
    const int doff0 = 0, doff1 = cN0, doff2 = cN0 + cN1,
              doffp0 = doff2 + cN2, doffp1 = doffp0 + cN1;

    // workspace layout (4B units); rec/float4 bases 8/16B-aligned
    int*   iws    = (int*)d_ws;
    int*   ideg   = iws;                         // 162500
    int*   cursor = ideg + 162500;               // 162500
    int*   rowptr = cursor + 162500;             // 162504
    int*   bsum   = rowptr + 162504;             // 704
    float* dinv   = (float*)(bsum + 704);        // 131256
    int2*  rec    = (int2*)(dinv + 131256);      // 915000 int2 (offset even)
    float* pos4   = (float*)(rec + 915000);      // 400000
    float* txbuf  = pos4 + 400000;               // 5 x 800000
    float* part   = txbuf + 5 * 800000;          // 4800000
    float* bufOut = part + 4800000;              // 3200000
    float* bufPool= bufOut + 3200000;            // 800000
    float* lpart  = bufPool + 800000;            // 5120

    // ---- independent prep ----
    k_pad4<<<gs(cN0), TPB, 0, stream>>>(pos, (float4*)pos4, cN0);

    // ---- batched CSR build ----
    Desc5 d;
    d.rows[0] = ei0;        d.cols[0] = ei0 + cE0; d.vals[0] = nullptr;
    d.rows[1] = ei1;        d.cols[1] = ei1 + cE1; d.vals[1] = nullptr;
    d.rows[2] = ei2;        d.cols[2] = ei2 + cE2; d.vals[2] = nullptr;
    d.rows[3] = d0r;        d.cols[3] = d0c;       d.vals[3] = d0v;
    d.rows[4] = d1r;        d.cols[4] = d1c;       d.vals[4] = d1v;
    d.eoff[0] = 0;
    d.eoff[1] = cE0;
    d.eoff[2] = cE0 + cE1;
    d.eoff[3] = Eg;
    d.eoff[4] = Eg + cN0;
    d.eoff[5] = Etot;
    d.doff[0] = doff0; d.doff[1] = doff1; d.doff[2] = doff2;
    d.doff[3] = doffp0; d.doff[4] = doffp1;

    hipMemsetAsync(ideg, 0, (size_t)162500 * 4, stream);
    k_count_all<<<gs(Etot), TPB, 0, stream>>>(d, ideg, Etot);
    int nb = (ntot + 255) / 256;
    k_scan1<<<nb, 256, 0, stream>>>(ideg, rowptr, bsum, dinv, ndinv, ntot);
    k_scan2<<<1, 64, 0, stream>>>(bsum, nb);
    k_scan3<<<nb, 256, 0, stream>>>(rowptr, cursor, bsum, ntot, Etot);
    k_scatter_all<<<gs(Etot), TPB, 0, stream>>>(d, cursor, rec, dinv, Etot);

    // ---- generic Tx recurrence ----
    auto run_sprops = [&](const float* x, int doffs, int n, int Cs, TxPtrs& txs) {
        const int* rp = rowptr + doffs;
        const float* dv = dinv + doffs;
        auto sprop = [&](const float* src, const float* prev, float* dst, int mode) {
            long long work = (long long)n * (Cs >> 2);
            if (Cs == 4)
                k_sprop_t<4><<<gs(work), TPB, 0, stream>>>(rp, rec, dv, src, prev, dst, n, mode);
            else if (Cs == 32)
                k_sprop_t<32><<<gs(work), TPB, 0, stream>>>(rp, rec, dv, src, prev, dst, n, mode);
            else
                k_sprop_t<64><<<gs(work), TPB, 0, stream>>>(rp, rec, dv, src, prev, dst, n, mode);
        };
        txs.p[0] = x;
        for (int i = 1; i < 6; ++i) txs.p[i] = txbuf + (long long)(i - 1) * 800000;
        sprop(txs.p[0], nullptr, (float*)txs.p[1], 0);
        for (int k = 2; k < 6; ++k)
            sprop(txs.p[k - 1], txs.p[k - 2], (float*)txs.p[k], 1);
    };

    // ---- layer 0: pos4 (N0x4, CIN=3) -> bufOut (N0x32); pool0 -> bufPool ----
    {
        TxPtrs txs;
        run_sprops(pos4, doff0, cN0, 4, txs);
        k_outgemm0<<<gs((long long)cN0 * 8), TPB, 0, stream>>>(bufOut, txs, W0, b0, cN0);
        k_spool4_t<32><<<gs((long long)cN1 * 8), TPB, 0, stream>>>(
            rowptr + doffp0, rec, bufOut, bufPool, cN1);
    }

    // ---- layer 1: bufPool (N1x32) -> part[0..2] (each N1x64); pool1 fused ----
    {
        TxPtrs txs;
        run_sprops(bufPool, doff1, cN1, 32, txs);
        const int pstride = cN1 * 64;  // 1600000
        k_outsplit_nt<32, 64, 3, 2><<<gs((long long)(cN1 / 2) * 16 * 3), TPB, 0, stream>>>(
            part, txs, W1, cN1, pstride);
        k_pool_f<64, 3><<<gs((long long)cN2 * 16), TPB, 0, stream>>>(
            rowptr + doffp1, rec, part, b1, bufPool, cN2, pstride);
    }

    // ---- layer 2: bufPool (N2x64) -> part[0..5] (each N2x128); head fused ----
    {
        TxPtrs txs;
        run_sprops(bufPool, doff2, cN2, 64, txs);
        const int pstride = cN2 * 128;  // 800000
        k_outsplit_nt<64, 128, 6, 2><<<gs((long long)(cN2 / 2) * 32 * 6), TPB, 0, stream>>>(
            part, txs, W2, cN2, pstride);
        k_linear_partial_f<<<NBLK, TPB, 0, stream>>>(
            lw, (const float4*)part, b2, lpart, cN2 * 128 / 4, cN2 * 128, NBLK);
        k_linear_final<<<1, 640, 0, stream>>>(lpart, lb, outZ, NBLK);
    }
}

// Round 10
// 288.450 us; speedup vs baseline: 1.5431x; 1.2014x over previous
//
#include <hip/hip_runtime.h>

// ChebNet classifier: 3x ChebConv(K=6) + 2x sparse pool + linear head.
// R9 post-mortem: scatter still 55us -- 8B random writes to lines shared
//     across XCDs (non-coherent L2s) -> each line flushed partially, 8x
//     write amplification. Count kernel same pattern (~25us).
// R10: two-phase binned CSR build. Phase A bins edges by row-bucket
//     (grow>>9) with per-block chunk reservation -> every binrec line is
//     written by ONE block. Phase B (1 block/bucket): LDS row count+scan
//     -> rowptr+dinv (B1), then final in-bucket placement (B2) with writes
//     confined to the bucket's contiguous single-block-owned region.

#define TPB 256
#define NB   318      // buckets = ceil(162500/512)
#define BCAP 8192     // per-bucket capacity (avg ~2900, fixed inputs)
#define EPB  4096     // edges per block, phase A

static inline int gs(long long n) { return (int)((n + TPB - 1) / TPB); }

struct Desc5 {
    const int* rows[5];
    const int* cols[5];
    const float* vals[5];
    int eoff[6];
    int doff[5];
};

struct TxPtrs { const float* p[6]; };

// ---------- phase A: bin edges by bucket with per-block chunk reservation ----------

__global__ void k_binA(Desc5 d, int* __restrict__ gbcnt, int2* __restrict__ binrec,
                       int Etot) {
    __shared__ int2 srec[EPB];
    __shared__ unsigned short sbuck[EPB];
    __shared__ int scnt[NB], sbase[NB], slcur[NB];
    int tid = threadIdx.x;
    int e0 = blockIdx.x * EPB;
    int ne = min(EPB, Etot - e0);
    for (int b = tid; b < NB; b += 256) scnt[b] = 0;
    __syncthreads();
    for (int i = tid; i < ne; i += 256) {
        int e = e0 + i;
        int s = 0;
        while (e >= d.eoff[s + 1]) ++s;
        int le = e - d.eoff[s];
        int grow = d.doff[s] + d.rows[s][le];
        int col = d.cols[s][le];
        int vb = (s >= 3) ? __float_as_int(d.vals[s][le]) : 0;
        int b = grow >> 9;
        srec[i] = make_int2(((grow & 511) << 17) | col, vb);
        sbuck[i] = (unsigned short)b;
        atomicAdd(&scnt[b], 1);
    }
    __syncthreads();
    for (int b = tid; b < NB; b += 256) {
        sbase[b] = scnt[b] > 0 ? atomicAdd(&gbcnt[b], scnt[b]) : 0;
        slcur[b] = 0;
    }
    __syncthreads();
    for (int i = tid; i < ne; i += 256) {
        int b = sbuck[i];
        int off = atomicAdd(&slcur[b], 1);
        binrec[(long long)b * BCAP + sbase[b] + off] = srec[i];
    }
}

// exclusive scan of gbcnt[NB] -> gbbase[NB] (1 block, 64 threads)
__global__ void k_bscan(const int* __restrict__ gbcnt, int* __restrict__ gbbase) {
    int lane = threadIdx.x;
    int carry = 0;
    for (int base = 0; base < NB; base += 64) {
        int i = base + lane;
        int v = (i < NB) ? gbcnt[i] : 0;
        int s = v;
#pragma unroll
        for (int off = 1; off < 64; off <<= 1) {
            int t = __shfl_up(s, off, 64);
            if (lane >= off) s += t;
        }
        if (i < NB) gbbase[i] = carry + s - v;
        carry += __shfl(s, 63, 64);
    }
}

// ---------- phase B common: LDS count + block scan over 512 rows ----------

__device__ inline void bucket_count_scan(const int2* __restrict__ br, int ne,
                                         int* cnt, int* lexcl, int* wsum) {
    int tid = threadIdx.x;
    cnt[2 * tid] = 0; cnt[2 * tid + 1] = 0;
    __syncthreads();
    for (int i = tid; i < ne; i += 256)
        atomicAdd(&cnt[br[i].x >> 17], 1);
    __syncthreads();
    int c0 = cnt[2 * tid], c1 = cnt[2 * tid + 1], p = c0 + c1;
    int lane = tid & 63, wid = tid >> 6;
    int s = p;
#pragma unroll
    for (int off = 1; off < 64; off <<= 1) {
        int t = __shfl_up(s, off, 64);
        if (lane >= off) s += t;
    }
    if (lane == 63) wsum[wid] = s;
    __syncthreads();
    int add = 0;
    for (int w = 0; w < wid; ++w) add += wsum[w];
    int ep = add + s - p;
    lexcl[2 * tid] = ep; lexcl[2 * tid + 1] = ep + c0;
    __syncthreads();
}

// B1: rowptr + dinv
__global__ void k_B1(const int* __restrict__ gbcnt, const int* __restrict__ gbbase,
                     const int2* __restrict__ binrec, int* __restrict__ rowptr,
                     float* __restrict__ dinv, int ntot, int ndinv, int Etot) {
    __shared__ int cnt[512], lexcl[512], wsum[4];
    int bucket = blockIdx.x, tid = threadIdx.x;
    int ne = gbcnt[bucket];
    const int2* br = binrec + (long long)bucket * BCAP;
    bucket_count_scan(br, ne, cnt, lexcl, wsum);
    int base = gbbase[bucket];
    int row0 = bucket << 9;
    int nrows = min(512, ntot - row0);
    for (int lr = tid; lr < nrows; lr += 256) {
        int grow = row0 + lr;
        rowptr[grow] = base + lexcl[lr];
        if (grow < ndinv) {
            int c = cnt[lr];
            dinv[grow] = c > 0 ? 1.0f / sqrtf((float)c) : 0.f;
        }
    }
    if (bucket == 0 && tid == 0) rowptr[ntot] = Etot;
}

// B2: place edges into final rec[] (writes confined to this bucket's region)
__global__ void k_B2(const int* __restrict__ gbcnt, const int* __restrict__ gbbase,
                     const int2* __restrict__ binrec, const float* __restrict__ dinv,
                     int2* __restrict__ rec) {
    __shared__ int cnt[512], lexcl[512], lcur[512], wsum[4];
    int bucket = blockIdx.x, tid = threadIdx.x;
    int ne = gbcnt[bucket];
    const int2* br = binrec + (long long)bucket * BCAP;
    bucket_count_scan(br, ne, cnt, lexcl, wsum);
    lcur[2 * tid] = 0; lcur[2 * tid + 1] = 0;
    __syncthreads();
    int base = gbbase[bucket];
    int row0 = bucket << 9;
    for (int i = tid; i < ne; i += 256) {
        int2 r = br[i];
        int lr = r.x >> 17, col = r.x & 0x1FFFF;
        int grow = row0 + lr;
        int pos = base + lexcl[lr] + atomicAdd(&lcur[lr], 1);
        float wv;
        if (grow < 100000)      wv = dinv[col];
        else if (grow < 125000) wv = dinv[100000 + col];
        else if (grow < 131250) wv = dinv[125000 + col];
        else                    wv = __int_as_float(r.y);
        rec[pos] = make_int2(col, __float_as_int(wv));
    }
}

// pos (N0 x 3) -> pos4 (N0 x 4, w = 0)
__global__ void k_pad4(const float* __restrict__ pos, float4* __restrict__ pos4, int n) {
    int i = blockIdx.x * blockDim.x + threadIdx.x;
    if (i < n) pos4[i] = make_float4(pos[3 * i], pos[3 * i + 1], pos[3 * i + 2], 0.f);
}

// ---------- gather SpMV (Cheb prop) ----------

template <int C>
__global__ void k_sprop_t(const int* __restrict__ rowptr, const int2* __restrict__ rec,
                          const float* __restrict__ dinv, const float* __restrict__ src,
                          const float* __restrict__ prev, float* __restrict__ dst,
                          int n, int mode) {
    constexpr int C4 = C / 4;
    int idx = blockIdx.x * blockDim.x + threadIdx.x;
    if (idx >= n * C4) return;
    int r = idx / C4, c4 = (idx - r * C4) * 4;
    int s0 = rowptr[r], s1 = rowptr[r + 1];
    float4 acca = make_float4(0.f, 0.f, 0.f, 0.f);
    float4 accb = make_float4(0.f, 0.f, 0.f, 0.f);
    int j = s0;
    for (; j + 2 <= s1; j += 2) {
        int2 ra = rec[j], rb = rec[j + 1];
        float wa = __int_as_float(ra.y), wb = __int_as_float(rb.y);
        float4 sa = *(const float4*)(src + (long long)ra.x * C + c4);
        float4 sb = *(const float4*)(src + (long long)rb.x * C + c4);
        acca.x += wa * sa.x; acca.y += wa * sa.y; acca.z += wa * sa.z; acca.w += wa * sa.w;
        accb.x += wb * sb.x; accb.y += wb * sb.y; accb.z += wb * sb.z; accb.w += wb * sb.w;
    }
    if (j < s1) {
        int2 rr = rec[j];
        float w = __int_as_float(rr.y);
        float4 s = *(const float4*)(src + (long long)rr.x * C + c4);
        acca.x += w * s.x; acca.y += w * s.y; acca.z += w * s.z; acca.w += w * s.w;
    }
    acca.x += accb.x; acca.y += accb.y; acca.z += accb.z; acca.w += accb.w;
    float m = -dinv[r];
    long long o = (long long)r * C + c4;
    float4 out;
    if (mode) {
        float4 p = *(const float4*)(prev + o);
        out.x = 2.f * m * acca.x - p.x; out.y = 2.f * m * acca.y - p.y;
        out.z = 2.f * m * acca.z - p.z; out.w = 2.f * m * acca.w - p.w;
    } else {
        out.x = m * acca.x; out.y = m * acca.y; out.z = m * acca.z; out.w = m * acca.w;
    }
    *(float4*)(dst + o) = out;
}

// ---------- pool0: out[r] = sum_j val_j * relu(x[col_j]) ----------

template <int C>
__global__ void k_spool4_t(const int* __restrict__ rowptr, const int2* __restrict__ rec,
                           const float* __restrict__ x, float* __restrict__ out, int n) {
    constexpr int C4 = C / 4;
    int idx = blockIdx.x * blockDim.x + threadIdx.x;
    if (idx >= n * C4) return;
    int r = idx / C4, c4 = (idx - r * C4) * 4;
    int s0 = rowptr[r], s1 = rowptr[r + 1];
    float4 acca = make_float4(0.f, 0.f, 0.f, 0.f);
    float4 accb = make_float4(0.f, 0.f, 0.f, 0.f);
    int j = s0;
    for (; j + 2 <= s1; j += 2) {
        int2 ra = rec[j], rb = rec[j + 1];
        float va = __int_as_float(ra.y), vb = __int_as_float(rb.y);
        float4 sa = *(const float4*)(x + (long long)ra.x * C + c4);
        float4 sb = *(const float4*)(x + (long long)rb.x * C + c4);
        acca.x += va * fmaxf(sa.x, 0.f); acca.y += va * fmaxf(sa.y, 0.f);
        acca.z += va * fmaxf(sa.z, 0.f); acca.w += va * fmaxf(sa.w, 0.f);
        accb.x += vb * fmaxf(sb.x, 0.f); accb.y += vb * fmaxf(sb.y, 0.f);
        accb.z += vb * fmaxf(sb.z, 0.f); accb.w += vb * fmaxf(sb.w, 0.f);
    }
    if (j < s1) {
        int2 rr = rec[j];
        float v = __int_as_float(rr.y);
        float4 s = *(const float4*)(x + (long long)rr.x * C + c4);
        acca.x += v * fmaxf(s.x, 0.f); acca.y += v * fmaxf(s.y, 0.f);
        acca.z += v * fmaxf(s.z, 0.f); acca.w += v * fmaxf(s.w, 0.f);
    }
    acca.x += accb.x; acca.y += accb.y; acca.z += accb.z; acca.w += accb.w;
    *(float4*)(out + (long long)r * C + c4) = acca;
}

// ---------- pool1 fused with layer-1 partial reduce + bias + relu ----------

template <int C, int KSPLIT>
__global__ void k_pool_f(const int* __restrict__ rowptr, const int2* __restrict__ rec,
                         const float* __restrict__ part, const float* __restrict__ bias,
                         float* __restrict__ out, int n, int partStride) {
    constexpr int C4 = C / 4;
    int idx = blockIdx.x * blockDim.x + threadIdx.x;
    if (idx >= n * C4) return;
    int r = idx / C4, c4 = (idx - r * C4) * 4;
    int s0 = rowptr[r], s1 = rowptr[r + 1];
    float4 bb = *(const float4*)(bias + c4);
    float4 acc = make_float4(0.f, 0.f, 0.f, 0.f);
    for (int j = s0; j < s1; ++j) {
        int2 rr = rec[j];
        float v = __int_as_float(rr.y);
        float4 x = bb;
#pragma unroll
        for (int s = 0; s < KSPLIT; ++s) {
            float4 p = *(const float4*)(part + (long long)s * partStride + (long long)rr.x * C + c4);
            x.x += p.x; x.y += p.y; x.z += p.z; x.w += p.w;
        }
        acc.x += v * fmaxf(x.x, 0.f); acc.y += v * fmaxf(x.y, 0.f);
        acc.z += v * fmaxf(x.z, 0.f); acc.w += v * fmaxf(x.w, 0.f);
    }
    *(float4*)(out + (long long)r * C + c4) = acc;
}

// ---------- layer-0 direct out-GEMM (CIN=3 stride 4, COUT=32) ----------

__global__ void k_outgemm0(float* __restrict__ out, TxPtrs txs,
                           const float* __restrict__ W, const float* __restrict__ b,
                           int n) {
    int idx = blockIdx.x * blockDim.x + threadIdx.x;
    if (idx >= n * 8) return;
    int node = idx >> 3, co = (idx & 7) * 4;
    float4 acc = *(const float4*)(b + co);
#pragma unroll
    for (int k = 0; k < 6; ++k) {
        float4 xv = ((const float4*)txs.p[k])[node];
        const float* Wk = W + k * 96 + co;
        float4 w0 = *(const float4*)(Wk);
        float4 w1 = *(const float4*)(Wk + 32);
        float4 w2 = *(const float4*)(Wk + 64);
        acc.x += xv.x * w0.x + xv.y * w1.x + xv.z * w2.x;
        acc.y += xv.x * w0.y + xv.y * w1.y + xv.z * w2.y;
        acc.z += xv.x * w0.z + xv.y * w1.z + xv.z * w2.z;
        acc.w += xv.x * w0.w + xv.y * w1.w + xv.z * w2.w;
    }
    *(float4*)(out + (long long)node * 32 + co) = acc;
}

// ---------- node-tiled k-split out-GEMM (NT=2, no spill) ----------

template <int CIN, int COUT, int KSPLIT, int NT>
__global__ __launch_bounds__(256, 4)
void k_outsplit_nt(float* __restrict__ part, TxPtrs txs,
                   const float* __restrict__ W, int n, int partStride) {
    constexpr int CO4 = COUT / 4;
    constexpr int KPER = 6 / KSPLIT;
    int ntile = n / NT;
    int per = ntile * CO4;
    int idx = blockIdx.x * blockDim.x + threadIdx.x;
    if (idx >= per * KSPLIT) return;
    int s = idx / per, t = idx - s * per;
    int tile = t / CO4, co = (t - tile * CO4) * 4;
    int node0 = tile * NT;
    float4 acc[NT];
#pragma unroll
    for (int i = 0; i < NT; ++i) acc[i] = make_float4(0.f, 0.f, 0.f, 0.f);
#pragma unroll
    for (int kk = 0; kk < KPER; ++kk) {
        int k = s * KPER + kk;
        const float* xb = txs.p[k] + (long long)node0 * CIN;
        const float* Wk = W + (long long)k * CIN * COUT + co;
#pragma unroll
        for (int c4 = 0; c4 < CIN / 4; ++c4) {
            float4 xv[NT];
#pragma unroll
            for (int i = 0; i < NT; ++i)
                xv[i] = *(const float4*)(xb + (long long)i * CIN + c4 * 4);
            const float* Wr = Wk + c4 * 4 * COUT;
            float4 w0 = *(const float4*)(Wr);
            float4 w1 = *(const float4*)(Wr + COUT);
            float4 w2 = *(const float4*)(Wr + 2 * COUT);
            float4 w3 = *(const float4*)(Wr + 3 * COUT);
#pragma unroll
            for (int i = 0; i < NT; ++i) {
                acc[i].x += xv[i].x * w0.x + xv[i].y * w1.x + xv[i].z * w2.x + xv[i].w * w3.x;
                acc[i].y += xv[i].x * w0.y + xv[i].y * w1.y + xv[i].z * w2.y + xv[i].w * w3.y;
                acc[i].z += xv[i].x * w0.z + xv[i].y * w1.z + xv[i].z * w2.z + xv[i].w * w3.z;
                acc[i].w += xv[i].x * w0.w + xv[i].y * w1.w + xv[i].z * w2.w + xv[i].w * w3.w;
            }
        }
    }
    float* op = part + (long long)s * partStride + (long long)node0 * COUT + co;
#pragma unroll
    for (int i = 0; i < NT; ++i)
        *(float4*)(op + (long long)i * COUT) = acc[i];
}

// ---------- linear head, fused with layer-2 partial reduce + bias ----------

__global__ void k_linear_partial_f(const float* __restrict__ lw,
                                   const float4* __restrict__ part,
                                   const float* __restrict__ b2,
                                   float* __restrict__ partials,
                                   int len4, int len, int nblk) {
    float acc[10];
#pragma unroll
    for (int j = 0; j < 10; ++j) acc[j] = 0.f;
    const float4* b2v = (const float4*)b2;
    for (int i = blockIdx.x * blockDim.x + threadIdx.x; i < len4;
         i += gridDim.x * blockDim.x) {
        float4 xv = b2v[i & 31];
#pragma unroll
        for (int s = 0; s < 6; ++s) {
            float4 p = part[s * 200000 + i];
            xv.x += p.x; xv.y += p.y; xv.z += p.z; xv.w += p.w;
        }
#pragma unroll
        for (int j = 0; j < 10; ++j) {
            float4 wv = *(const float4*)(lw + (long long)j * len + i * 4);
            acc[j] += xv.x * wv.x + xv.y * wv.y + xv.z * wv.z + xv.w * wv.w;
        }
    }
    __shared__ float lds[4][10];
    int wid = threadIdx.x >> 6, lane = threadIdx.x & 63;
#pragma unroll
    for (int j = 0; j < 10; ++j) {
        float v = acc[j];
        for (int off = 32; off > 0; off >>= 1) v += __shfl_down(v, off, 64);
        if (lane == 0) lds[wid][j] = v;
    }
    __syncthreads();
    if (threadIdx.x < 10) {
        float s = lds[0][threadIdx.x] + lds[1][threadIdx.x] +
                  lds[2][threadIdx.x] + lds[3][threadIdx.x];
        partials[threadIdx.x * nblk + blockIdx.x] = s;
    }
}

__global__ void k_linear_final(const float* __restrict__ partials,
                               const float* __restrict__ lb,
                               float* __restrict__ out, int nblk) {
    int j = threadIdx.x >> 6, lane = threadIdx.x & 63;
    float v = 0.f;
    for (int b = lane; b < nblk; b += 64) v += partials[j * nblk + b];
    for (int off = 32; off > 0; off >>= 1) v += __shfl_down(v, off, 64);
    if (lane == 0) out[j] = lb[j] + v;
}

extern "C" void kernel_launch(void* const* d_in, const int* in_sizes, int n_in,
                              void* d_out, int out_size, void* d_ws, size_t ws_size,
                              hipStream_t stream) {
    const int cN0 = 100000, cN1 = 25000, cN2 = 6250;
    const int cE0 = 600000, cE1 = 150000, cE2 = 40000;
    const int NBLK = 512;

    const float* pos = (const float*)d_in[0];
    const int*   ei0 = (const int*)d_in[1];
    const int*   ei1 = (const int*)d_in[2];
    const int*   ei2 = (const int*)d_in[3];
    const int*   d0r = (const int*)d_in[4];
    const int*   d0c = (const int*)d_in[5];
    const float* d0v = (const float*)d_in[6];
    const int*   d1r = (const int*)d_in[7];
    const int*   d1c = (const int*)d_in[8];
    const float* d1v = (const float*)d_in[9];
    const float* W0  = (const float*)d_in[10];
    const float* b0  = (const float*)d_in[11];
    const float* W1  = (const float*)d_in[12];
    const float* b1  = (const float*)d_in[13];
    const float* W2  = (const float*)d_in[14];
    const float* b2  = (const float*)d_in[15];
    const float* lw  = (const float*)d_in[16];
    const float* lb  = (const float*)d_in[17];
    float* outZ = (float*)d_out;

    // concatenated row space: g0 g1 g2 p0 p1
    const int ntot = cN0 + cN1 + cN2 + cN1 + cN2;          // 162500
    const int Etot = cE0 + cE1 + cE2 + cN0 + cN1;          // 915000
    const int Eg   = cE0 + cE1 + cE2;                      // 790000
    const int ndinv = cN0 + cN1 + cN2;                     // 131250
    const int doff0 = 0, doff1 = cN0, doff2 = cN0 + cN1,
              doffp0 = doff2 + cN2, doffp1 = doffp0 + cN1;

    // workspace layout (4B units); int2/float4 bases 8/16B-aligned
    int*   iws    = (int*)d_ws;
    int*   gbcnt  = iws;                          // 320
    int*   gbbase = gbcnt + 320;                  // 320
    int*   rowptr = gbbase + 320;                 // 162504
    float* dinv   = (float*)(rowptr + 162504);    // 131256
    int2*  binrec = (int2*)(dinv + 131256);       // NB*BCAP int2 (even offset)
    int2*  rec    = binrec + (long long)NB * BCAP;// 915000 int2
    float* pos4   = (float*)(rec + 915000);       // 400000 (16B aligned)
    float* txbuf  = pos4 + 400000;                // 5 x 800000
    float* part   = txbuf + 5 * 800000;           // 4800000
    float* bufOut = part + 4800000;               // 3200000
    float* bufPool= bufOut + 3200000;             // 800000
    float* lpart  = bufPool + 800000;             // 5120

    // ---- independent prep ----
    k_pad4<<<gs(cN0), TPB, 0, stream>>>(pos, (float4*)pos4, cN0);

    Desc5 d;
    d.rows[0] = ei0;        d.cols[0] = ei0 + cE0; d.vals[0] = nullptr;
    d.rows[1] = ei1;        d.cols[1] = ei1 + cE1; d.vals[1] = nullptr;
    d.rows[2] = ei2;        d.cols[2] = ei2 + cE2; d.vals[2] = nullptr;
    d.rows[3] = d0r;        d.cols[3] = d0c;       d.vals[3] = d0v;
    d.rows[4] = d1r;        d.cols[4] = d1c;       d.vals[4] = d1v;
    d.eoff[0] = 0;
    d.eoff[1] = cE0;
    d.eoff[2] = cE0 + cE1;
    d.eoff[3] = Eg;
    d.eoff[4] = Eg + cN0;
    d.eoff[5] = Etot;
    d.doff[0] = doff0; d.doff[1] = doff1; d.doff[2] = doff2;
    d.doff[3] = doffp0; d.doff[4] = doffp1;

    // ---- binned CSR build ----
    hipMemsetAsync(gbcnt, 0, (size_t)NB * 4, stream);
    k_binA<<<(Etot + EPB - 1) / EPB, TPB, 0, stream>>>(d, gbcnt, binrec, Etot);
    k_bscan<<<1, 64, 0, stream>>>(gbcnt, gbbase);
    k_B1<<<NB, TPB, 0, stream>>>(gbcnt, gbbase, binrec, rowptr, dinv, ntot, ndinv, Etot);
    k_B2<<<NB, TPB, 0, stream>>>(gbcnt, gbbase, binrec, dinv, rec);

    // ---- generic Tx recurrence ----
    auto run_sprops = [&](const float* x, int doffs, int n, int Cs, TxPtrs& txs) {
        const int* rp = rowptr + doffs;
        const float* dv = dinv + doffs;
        auto sprop = [&](const float* src, const float* prev, float* dst, int mode) {
            long long work = (long long)n * (Cs >> 2);
            if (Cs == 4)
                k_sprop_t<4><<<gs(work), TPB, 0, stream>>>(rp, rec, dv, src, prev, dst, n, mode);
            else if (Cs == 32)
                k_sprop_t<32><<<gs(work), TPB, 0, stream>>>(rp, rec, dv, src, prev, dst, n, mode);
            else
                k_sprop_t<64><<<gs(work), TPB, 0, stream>>>(rp, rec, dv, src, prev, dst, n, mode);
        };
        txs.p[0] = x;
        for (int i = 1; i < 6; ++i) txs.p[i] = txbuf + (long long)(i - 1) * 800000;
        sprop(txs.p[0], nullptr, (float*)txs.p[1], 0);
        for (int k = 2; k < 6; ++k)
            sprop(txs.p[k - 1], txs.p[k - 2], (float*)txs.p[k], 1);
    };

    // ---- layer 0: pos4 (N0x4, CIN=3) -> bufOut (N0x32); pool0 -> bufPool ----
    {
        TxPtrs txs;
        run_sprops(pos4, doff0, cN0, 4, txs);
        k_outgemm0<<<gs((long long)cN0 * 8), TPB, 0, stream>>>(bufOut, txs, W0, b0, cN0);
        k_spool4_t<32><<<gs((long long)cN1 * 8), TPB, 0, stream>>>(
            rowptr + doffp0, rec, bufOut, bufPool, cN1);
    }

    // ---- layer 1: bufPool (N1x32) -> part[0..2] (each N1x64); pool1 fused ----
    {
        TxPtrs txs;
        run_sprops(bufPool, doff1, cN1, 32, txs);
        const int pstride = cN1 * 64;  // 1600000
        k_outsplit_nt<32, 64, 3, 2><<<gs((long long)(cN1 / 2) * 16 * 3), TPB, 0, stream>>>(
            part, txs, W1, cN1, pstride);
        k_pool_f<64, 3><<<gs((long long)cN2 * 16), TPB, 0, stream>>>(
            rowptr + doffp1, rec, part, b1, bufPool, cN2, pstride);
    }

    // ---- layer 2: bufPool (N2x64) -> part[0..5] (each N2x128); head fused ----
    {
        TxPtrs txs;
        run_sprops(bufPool, doff2, cN2, 64, txs);
        const int pstride = cN2 * 128;  // 800000
        k_outsplit_nt<64, 128, 6, 2><<<gs((long long)(cN2 / 2) * 32 * 6), TPB, 0, stream>>>(
            part, txs, W2, cN2, pstride);
        k_linear_partial_f<<<NBLK, TPB, 0, stream>>>(
            lw, (const float4*)part, b2, lpart, cN2 * 128 / 4, cN2 * 128, NBLK);
        k_linear_final<<<1, 640, 0, stream>>>(lpart, lb, outZ, NBLK);
    }
}